// Round 1
// baseline (422.473 us; speedup 1.0000x reference)
//
#include <hip/hip_runtime.h>

#define T_STEPS 144000
#define HDIM 128
#define G4 512
#define NB 10
#define CH 16
#define EPS 1e-6f
#define WIN 32

__device__ __forceinline__ float sigf(float x){ return 1.f/(1.f+__expf(-x)); }
__device__ __forceinline__ float tanh_(float x){
  float e2 = __expf(-2.f*fabsf(x));
  float r = (1.f - e2)/(1.f + e2);
  return copysignf(r, x);
}

// ---------------- K1: encoder MLP + xproj0 + w_ih1 transpose ----------------
__global__ void k1_setup(const float* __restrict__ x, const float* __restrict__ w1, const float* __restrict__ b1,
                         const float* __restrict__ w2, const float* __restrict__ b2,
                         const float* __restrict__ w_ih0, const float* __restrict__ b_ih0, const float* __restrict__ b_hh0,
                         const float* __restrict__ w_ih1,
                         float* __restrict__ xproj0, float* __restrict__ wih1T)
{
  __shared__ float lat1[2][64];
  __shared__ float lat2[2][128];
  const int tid = threadIdx.x;
  if (tid < 128) {
    int b = tid >> 6, jj = tid & 63;
    float a = b1[jj];
    #pragma unroll
    for (int k = 0; k < 16; k++) a += x[b*16+k] * w1[jj*16+k];
    lat1[b][jj] = fmaxf(a, 0.f);
  }
  __syncthreads();
  {
    int b = tid >> 7, jj = tid & 127;
    float a = b2[jj];
    #pragma unroll
    for (int k = 0; k < 64; k++) a += lat1[b][k] * w2[jj*64+k];
    lat2[b][jj] = fmaxf(a, 0.f);
  }
  __syncthreads();
  for (int idx = tid; idx < 2*G4; idx += 256) {
    int b = idx >> 9, jj = idx & 511;
    float a = b_ih0[jj] + b_hh0[jj];
    #pragma unroll
    for (int k = 0; k < 128; k++) a += lat2[b][k] * w_ih0[jj*128+k];
    xproj0[idx] = a;
  }
  // transpose w_ih1 [512][128] -> wih1T [128][512]
  for (int idx = tid; idx < G4*HDIM; idx += 256) {
    int k = idx >> 9, jj = idx & 511;
    wih1T[idx] = w_ih1[jj*128 + k];
  }
}

// ---------------- K2: layer-0 recurrence (autonomous), convergence detect ----------------
__global__ __launch_bounds__(512) void k2_lstm0(const float* __restrict__ xproj0, const float* __restrict__ w_hh0,
                                                float* __restrict__ hs0, int* __restrict__ T0out)
{
  const int b = blockIdx.x, j = threadIdx.x;
  __shared__ __align__(16) float hls[HDIM];
  __shared__ float gls[G4];
  __shared__ int stop;
  float4 w4[32];
  const float4* wr = (const float4*)(w_hh0 + j*128);
  #pragma unroll
  for (int k = 0; k < 32; k++) w4[k] = wr[k];
  const float xp = xproj0[b*G4 + j];
  float* hb = hs0 + (size_t)b * T_STEPS * HDIM;
  if (j == 0) stop = 0;
  if (j < HDIM) hls[j] = 0.f;
  float c0 = 0.f, c1 = 0.f, h0p = 0.f, h1p = 0.f;
  int cnt = 0;
  __syncthreads();
  int t = 0;
  for (; t < T_STEPS; ++t) {
    float a0 = xp, a1 = 0.f, a2 = 0.f, a3 = 0.f;
    const float4* h4 = (const float4*)hls;
    #pragma unroll
    for (int k = 0; k < 32; k++) {
      float4 hv = h4[k];
      a0 += w4[k].x*hv.x; a1 += w4[k].y*hv.y; a2 += w4[k].z*hv.z; a3 += w4[k].w*hv.w;
    }
    gls[j] = (a0+a1)+(a2+a3);
    __syncthreads();
    if (j < 64) {
      float i0 = sigf(gls[j]),      f0 = sigf(gls[128+j]), g0 = tanh_(gls[256+j]), o0 = sigf(gls[384+j]);
      float i1 = sigf(gls[64+j]),   f1 = sigf(gls[192+j]), g1 = tanh_(gls[320+j]), o1 = sigf(gls[448+j]);
      float nc0 = f0*c0 + i0*g0, nc1 = f1*c1 + i1*g1;
      float nh0 = o0*tanh_(nc0), nh1 = o1*tanh_(nc1);
      bool ok = fabsf(nh0-h0p) <= EPS && fabsf(nh1-h1p) <= EPS
             && fabsf(nc0-c0) <= EPS*fmaxf(1.f, fabsf(nc0))
             && fabsf(nc1-c1) <= EPS*fmaxf(1.f, fabsf(nc1));
      c0 = nc0; c1 = nc1; h0p = nh0; h1p = nh1;
      hls[j] = nh0; hls[j+64] = nh1;
      hb[(size_t)t*HDIM + j] = nh0; hb[(size_t)t*HDIM + j + 64] = nh1;
      unsigned long long bal = __ballot(ok);
      cnt = (bal == ~0ull) ? cnt + 1 : 0;
      if (cnt >= WIN && j == 0) stop = 1;
    }
    __syncthreads();
    if (stop) { ++t; break; }
  }
  if (j == 0) T0out[b] = t;   // t = stop step + 1, or T_STEPS
}

// ---------------- K3: layer-1 recurrence + fused head ----------------
__global__ __launch_bounds__(512) void k3_lstm1(const float* __restrict__ wih1T, const float* __restrict__ w_hh1,
                                                const float* __restrict__ b_ih1, const float* __restrict__ b_hh1,
                                                const float* __restrict__ hs0, const int* __restrict__ T0in,
                                                const float* __restrict__ w_out, const float* __restrict__ b_out,
                                                float* __restrict__ out, int* __restrict__ T1out, float* __restrict__ outstar)
{
  const int b = blockIdx.x, j = threadIdx.x;
  __shared__ __align__(16) float hls[HDIM];
  __shared__ float gls[G4];
  __shared__ __align__(16) float xpls[CH*G4];   // 32 KB
  __shared__ __align__(16) float s0ls[CH*HDIM]; //  8 KB
  __shared__ int stop;
  float4 w4[32];
  const float4* wr = (const float4*)(w_hh1 + j*128);
  #pragma unroll
  for (int k = 0; k < 32; k++) w4[k] = wr[k];
  const float bias = b_ih1[j] + b_hh1[j];
  const int T0 = T0in[b];
  const int hn = j >> 5, hseg = j & 31;
  float4 wo = make_float4(0.f,0.f,0.f,0.f); float bo = 0.f;
  if (j < 320) { wo = ((const float4*)(w_out + hn*128))[hseg]; bo = b_out[hn]; }
  float* outb = out + (size_t)b * T_STEPS * NB;
  const float* hsb = hs0 + (size_t)b * T_STEPS * HDIM;
  if (j == 0) stop = 0;
  if (j < HDIM) hls[j] = 0.f;
  float c0 = 0.f, c1 = 0.f, h0p = 0.f, h1p = 0.f;
  int cnt = 0;
  __syncthreads();
  int t = 0;

  // -------- Phase A: t < T0 (time-varying input from hs0) --------
  while (t < T0) {
    const int C = min(CH, T0 - t);
    for (int idx = j; idx < CH*HDIM; idx += 512) {
      float v = 0.f;
      if (idx < C*HDIM) v = hsb[(size_t)t*HDIM + idx];
      s0ls[idx] = v;
    }
    __syncthreads();
    float xpa[CH];
    #pragma unroll
    for (int c = 0; c < CH; c++) xpa[c] = 0.f;
    const float4* s04 = (const float4*)s0ls;
    for (int k4 = 0; k4 < 32; k4++) {
      float wv0 = wih1T[(4*k4+0)*G4 + j];
      float wv1 = wih1T[(4*k4+1)*G4 + j];
      float wv2 = wih1T[(4*k4+2)*G4 + j];
      float wv3 = wih1T[(4*k4+3)*G4 + j];
      #pragma unroll
      for (int c = 0; c < CH; c++) {
        float4 sv = s04[c*32 + k4];
        xpa[c] += wv0*sv.x + wv1*sv.y + wv2*sv.z + wv3*sv.w;
      }
    }
    #pragma unroll
    for (int c = 0; c < CH; c++) xpls[c*G4 + j] = xpa[c];
    for (int c = 0; c < C; c++) {
      float a0 = xpls[c*G4 + j] + bias, a1 = 0.f, a2 = 0.f, a3 = 0.f;
      const float4* h4 = (const float4*)hls;
      #pragma unroll
      for (int k = 0; k < 32; k++) {
        float4 hv = h4[k];
        a0 += w4[k].x*hv.x; a1 += w4[k].y*hv.y; a2 += w4[k].z*hv.z; a3 += w4[k].w*hv.w;
      }
      gls[j] = (a0+a1)+(a2+a3);
      __syncthreads();
      if (j < 64) {
        float i0 = sigf(gls[j]),    f0 = sigf(gls[128+j]), g0 = tanh_(gls[256+j]), o0 = sigf(gls[384+j]);
        float i1 = sigf(gls[64+j]), f1 = sigf(gls[192+j]), g1 = tanh_(gls[320+j]), o1 = sigf(gls[448+j]);
        float nc0 = f0*c0 + i0*g0, nc1 = f1*c1 + i1*g1;
        float nh0 = o0*tanh_(nc0), nh1 = o1*tanh_(nc1);
        c0 = nc0; c1 = nc1; h0p = nh0; h1p = nh1;
        hls[j] = nh0; hls[j+64] = nh1;
      }
      __syncthreads();
      if (j < 320) {
        float4 hv = ((const float4*)hls)[hseg];
        float acc = wo.x*hv.x + wo.y*hv.y + wo.z*hv.z + wo.w*hv.w;
        acc += __shfl_xor(acc, 1, 32);
        acc += __shfl_xor(acc, 2, 32);
        acc += __shfl_xor(acc, 4, 32);
        acc += __shfl_xor(acc, 8, 32);
        acc += __shfl_xor(acc, 16, 32);
        if (hseg == 0) outb[(size_t)(t+c)*NB + hn] = acc + bo;
      }
      __syncthreads();
    }
    t += C;
  }

  // -------- Phase B: t >= T0 (constant input), with convergence detect --------
  if (T0 < T_STEPS) {
    if (j < HDIM) s0ls[j] = hsb[(size_t)(T0-1)*HDIM + j];
    __syncthreads();
    float xps = bias;
    const float4* s04 = (const float4*)s0ls;
    #pragma unroll
    for (int k4 = 0; k4 < 32; k4++) {
      float4 sv = s04[k4];
      xps += wih1T[(4*k4+0)*G4 + j]*sv.x + wih1T[(4*k4+1)*G4 + j]*sv.y
           + wih1T[(4*k4+2)*G4 + j]*sv.z + wih1T[(4*k4+3)*G4 + j]*sv.w;
    }
    for (; t < T_STEPS; ++t) {
      float a0 = xps, a1 = 0.f, a2 = 0.f, a3 = 0.f;
      const float4* h4 = (const float4*)hls;
      #pragma unroll
      for (int k = 0; k < 32; k++) {
        float4 hv = h4[k];
        a0 += w4[k].x*hv.x; a1 += w4[k].y*hv.y; a2 += w4[k].z*hv.z; a3 += w4[k].w*hv.w;
      }
      gls[j] = (a0+a1)+(a2+a3);
      __syncthreads();
      if (j < 64) {
        float i0 = sigf(gls[j]),    f0 = sigf(gls[128+j]), g0 = tanh_(gls[256+j]), o0 = sigf(gls[384+j]);
        float i1 = sigf(gls[64+j]), f1 = sigf(gls[192+j]), g1 = tanh_(gls[320+j]), o1 = sigf(gls[448+j]);
        float nc0 = f0*c0 + i0*g0, nc1 = f1*c1 + i1*g1;
        float nh0 = o0*tanh_(nc0), nh1 = o1*tanh_(nc1);
        bool ok = fabsf(nh0-h0p) <= EPS && fabsf(nh1-h1p) <= EPS
               && fabsf(nc0-c0) <= EPS*fmaxf(1.f, fabsf(nc0))
               && fabsf(nc1-c1) <= EPS*fmaxf(1.f, fabsf(nc1));
        c0 = nc0; c1 = nc1; h0p = nh0; h1p = nh1;
        hls[j] = nh0; hls[j+64] = nh1;
        unsigned long long bal = __ballot(ok);
        cnt = (bal == ~0ull) ? cnt + 1 : 0;
        if (cnt >= WIN && j == 0) stop = 1;
      }
      __syncthreads();
      if (j < 320) {
        float4 hv = ((const float4*)hls)[hseg];
        float acc = wo.x*hv.x + wo.y*hv.y + wo.z*hv.z + wo.w*hv.w;
        acc += __shfl_xor(acc, 1, 32);
        acc += __shfl_xor(acc, 2, 32);
        acc += __shfl_xor(acc, 4, 32);
        acc += __shfl_xor(acc, 8, 32);
        acc += __shfl_xor(acc, 16, 32);
        if (hseg == 0) outb[(size_t)t*NB + hn] = acc + bo;
      }
      __syncthreads();
      if (stop) { ++t; break; }
    }
  }
  if (j == 0) T1out[b] = t;
  // out* from the final h (valid frozen value when T1 < T_STEPS)
  if (j < 320) {
    float4 hv = ((const float4*)hls)[hseg];
    float acc = wo.x*hv.x + wo.y*hv.y + wo.z*hv.z + wo.w*hv.w;
    acc += __shfl_xor(acc, 1, 32);
    acc += __shfl_xor(acc, 2, 32);
    acc += __shfl_xor(acc, 4, 32);
    acc += __shfl_xor(acc, 8, 32);
    acc += __shfl_xor(acc, 16, 32);
    if (hseg == 0) outstar[b*NB + hn] = acc + bo;
  }
}

// ---------------- K4: fill t >= T1 with out* ----------------
__global__ void k4_fill(const int* __restrict__ T1in, const float* __restrict__ outstar, float* __restrict__ out)
{
  int idx = blockIdx.x*256 + threadIdx.x;
  if (idx >= 2*T_STEPS*NB) return;
  int n = idx % NB;
  int bt = idx / NB;
  int t = bt % T_STEPS;
  int b = bt / T_STEPS;
  if (t >= T1in[b]) out[idx] = outstar[b*NB + n];
}

extern "C" void kernel_launch(void* const* d_in, const int* in_sizes, int n_in,
                              void* d_out, int out_size, void* d_ws, size_t ws_size,
                              hipStream_t stream) {
  const float* x     = (const float*)d_in[0];
  const float* w1    = (const float*)d_in[1];
  const float* b1    = (const float*)d_in[2];
  const float* w2    = (const float*)d_in[3];
  const float* b2    = (const float*)d_in[4];
  const float* w_ih0 = (const float*)d_in[5];
  const float* w_hh0 = (const float*)d_in[6];
  const float* b_ih0 = (const float*)d_in[7];
  const float* b_hh0 = (const float*)d_in[8];
  const float* w_ih1 = (const float*)d_in[9];
  const float* w_hh1 = (const float*)d_in[10];
  const float* b_ih1 = (const float*)d_in[11];
  const float* b_hh1 = (const float*)d_in[12];
  const float* w_out = (const float*)d_in[13];
  const float* b_out = (const float*)d_in[14];
  float* out = (float*)d_out;

  char* ws = (char*)d_ws;
  float* xproj0  = (float*)(ws + 0);        // 2*512*4   = 4096 B
  float* wih1T   = (float*)(ws + 4096);     // 128*512*4 = 262144 B
  int*   T0      = (int*)  (ws + 266240);   // 8 B
  int*   T1      = (int*)  (ws + 266248);   // 8 B
  float* outstar = (float*)(ws + 266256);   // 80 B
  float* hs0     = (float*)(ws + 270336);   // 2*144000*128*4 = 147456000 B

  k1_setup<<<1, 256, 0, stream>>>(x, w1, b1, w2, b2, w_ih0, b_ih0, b_hh0, w_ih1, xproj0, wih1T);
  k2_lstm0<<<2, 512, 0, stream>>>(xproj0, w_hh0, hs0, T0);
  k3_lstm1<<<2, 512, 0, stream>>>(wih1T, w_hh1, b_ih1, b_hh1, hs0, T0, w_out, b_out, out, T1, outstar);
  k4_fill<<<11250, 256, 0, stream>>>(T1, outstar, out);
}

// Round 2
// 288.306 us; speedup vs baseline: 1.4654x; 1.4654x over previous
//
#include <hip/hip_runtime.h>

#define T_STEPS 144000
#define HDIM 128
#define G4 512
#define NB 10
#define CH 16
#define EPS 1e-5f
#define WIN 16

__device__ __forceinline__ float sigf(float x){ return 1.f/(1.f+__expf(-x)); }
__device__ __forceinline__ float tanh_(float x){
  float e2 = __expf(-2.f*fabsf(x));
  float r = (1.f - e2)/(1.f + e2);
  return copysignf(r, x);
}

// ---------------- K1: encoder MLP + xproj0 + w_ih1 transpose ----------------
__global__ void k1_setup(const float* __restrict__ x, const float* __restrict__ w1, const float* __restrict__ b1,
                         const float* __restrict__ w2, const float* __restrict__ b2,
                         const float* __restrict__ w_ih0, const float* __restrict__ b_ih0, const float* __restrict__ b_hh0,
                         const float* __restrict__ w_ih1,
                         float* __restrict__ xproj0, float* __restrict__ wih1T)
{
  __shared__ float lat1[2][64];
  __shared__ float lat2[2][128];
  const int tid = threadIdx.x;
  if (tid < 128) {
    int b = tid >> 6, jj = tid & 63;
    float a = b1[jj];
    #pragma unroll
    for (int k = 0; k < 16; k++) a += x[b*16+k] * w1[jj*16+k];
    lat1[b][jj] = fmaxf(a, 0.f);
  }
  __syncthreads();
  {
    int b = tid >> 7, jj = tid & 127;
    float a = b2[jj];
    #pragma unroll
    for (int k = 0; k < 64; k++) a += lat1[b][k] * w2[jj*64+k];
    lat2[b][jj] = fmaxf(a, 0.f);
  }
  __syncthreads();
  for (int idx = tid; idx < 2*G4; idx += 256) {
    int b = idx >> 9, jj = idx & 511;
    float a = b_ih0[jj] + b_hh0[jj];
    #pragma unroll
    for (int k = 0; k < 128; k++) a += lat2[b][k] * w_ih0[jj*128+k];
    xproj0[idx] = a;
  }
  // transpose w_ih1 [512][128] -> wih1T [128][512]
  for (int idx = tid; idx < G4*HDIM; idx += 256) {
    int k = idx >> 9, jj = idx & 511;
    wih1T[idx] = w_ih1[jj*128 + k];
  }
}

// ---------------- K2: layer-0 recurrence (autonomous), convergence detect ----------------
__global__ __launch_bounds__(512) void k2_lstm0(const float* __restrict__ xproj0, const float* __restrict__ w_hh0,
                                                float* __restrict__ hs0, int* __restrict__ T0out)
{
  const int b = blockIdx.x, j = threadIdx.x;
  __shared__ __align__(16) float hls[HDIM];
  __shared__ float gls[G4];
  __shared__ int okw[2];
  float4 w4[32];
  const float4* wr = (const float4*)(w_hh0 + j*128);
  #pragma unroll
  for (int k = 0; k < 32; k++) w4[k] = wr[k];
  const float xp = xproj0[b*G4 + j];
  float* hb = hs0 + (size_t)b * T_STEPS * HDIM;
  if (j < HDIM) hls[j] = 0.f;
  float c = 0.f, hp = 0.f;
  int cnt = 0;
  __syncthreads();
  int t = 0;
  for (; t < T_STEPS; ++t) {
    float a0 = xp, a1 = 0.f, a2 = 0.f, a3 = 0.f;
    const float4* h4 = (const float4*)hls;
    #pragma unroll
    for (int k = 0; k < 32; k++) {
      float4 hv = h4[k];
      a0 += w4[k].x*hv.x; a1 += w4[k].y*hv.y; a2 += w4[k].z*hv.z; a3 += w4[k].w*hv.w;
    }
    gls[j] = (a0+a1)+(a2+a3);
    __syncthreads();
    if (j < HDIM) {
      float i = sigf(gls[j]), f = sigf(gls[128+j]), g = tanh_(gls[256+j]), o = sigf(gls[384+j]);
      float nc = f*c + i*g;
      float nh = o*tanh_(nc);
      bool ok = fabsf(nh-hp) <= EPS && fabsf(nc-c) <= EPS*fmaxf(1.f, fabsf(nc));
      c = nc; hp = nh;
      hls[j] = nh;
      hb[(size_t)t*HDIM + j] = nh;
      unsigned long long bal = __ballot(ok);
      if ((j & 63) == 0) okw[j >> 6] = (bal == ~0ull) ? 1 : 0;
    }
    __syncthreads();
    cnt = (okw[0] && okw[1]) ? cnt + 1 : 0;
    if (cnt >= WIN) { ++t; break; }
  }
  if (j == 0) T0out[b] = t;   // t = stop step + 1, or T_STEPS
}

// ---------------- K3: layer-1 recurrence + fused head (head barrier-free) ----------------
__global__ __launch_bounds__(512) void k3_lstm1(const float* __restrict__ wih1T, const float* __restrict__ w_hh1,
                                                const float* __restrict__ b_ih1, const float* __restrict__ b_hh1,
                                                const float* __restrict__ hs0, const int* __restrict__ T0in,
                                                const float* __restrict__ w_out, const float* __restrict__ b_out,
                                                float* __restrict__ out, int* __restrict__ T1out, float* __restrict__ outstar)
{
  const int b = blockIdx.x, j = threadIdx.x;
  __shared__ __align__(16) float hls[HDIM];
  __shared__ float gls[G4];
  __shared__ __align__(16) float s0ls[CH*HDIM]; //  8 KB
  __shared__ int okw[2];
  float4 w4[32];
  const float4* wr = (const float4*)(w_hh1 + j*128);
  #pragma unroll
  for (int k = 0; k < 32; k++) w4[k] = wr[k];
  const float bias = b_ih1[j] + b_hh1[j];
  const int T0 = T0in[b];
  const int hn = j >> 5, hseg = j & 31;
  float4 wo = make_float4(0.f,0.f,0.f,0.f); float bo = 0.f;
  if (j < 320) { wo = ((const float4*)(w_out + hn*128))[hseg]; bo = b_out[hn]; }
  float* outb = out + (size_t)b * T_STEPS * NB;
  const float* hsb = hs0 + (size_t)b * T_STEPS * HDIM;
  if (j < HDIM) hls[j] = 0.f;
  float c = 0.f, hp = 0.f;
  int cnt = 0;
  __syncthreads();
  int t = 0;

  // -------- Phase A: t < T0 (time-varying input from hs0) --------
  while (t < T0) {
    const int C = min(CH, T0 - t);
    for (int idx = j; idx < CH*HDIM; idx += 512) {
      float v = 0.f;
      if (idx < C*HDIM) v = hsb[(size_t)t*HDIM + idx];
      s0ls[idx] = v;
    }
    __syncthreads();
    float xpa[CH];
    #pragma unroll
    for (int cc = 0; cc < CH; cc++) xpa[cc] = 0.f;
    const float4* s04 = (const float4*)s0ls;
    for (int k4 = 0; k4 < 32; k4++) {
      float wv0 = wih1T[(4*k4+0)*G4 + j];
      float wv1 = wih1T[(4*k4+1)*G4 + j];
      float wv2 = wih1T[(4*k4+2)*G4 + j];
      float wv3 = wih1T[(4*k4+3)*G4 + j];
      #pragma unroll
      for (int cc = 0; cc < CH; cc++) {
        float4 sv = s04[cc*32 + k4];
        xpa[cc] += wv0*sv.x + wv1*sv.y + wv2*sv.z + wv3*sv.w;
      }
    }
    for (int cc = 0; cc < C; cc++) {
      float a0 = xpa[cc] + bias, a1 = 0.f, a2 = 0.f, a3 = 0.f;
      const float4* h4 = (const float4*)hls;
      #pragma unroll
      for (int k = 0; k < 32; k++) {
        float4 hv = h4[k];
        a0 += w4[k].x*hv.x; a1 += w4[k].y*hv.y; a2 += w4[k].z*hv.z; a3 += w4[k].w*hv.w;
      }
      gls[j] = (a0+a1)+(a2+a3);
      __syncthreads();
      if (j < HDIM) {
        float i = sigf(gls[j]), f = sigf(gls[128+j]), g = tanh_(gls[256+j]), o = sigf(gls[384+j]);
        float nc = f*c + i*g;
        float nh = o*tanh_(nc);
        c = nc; hp = nh;
        hls[j] = nh;
      }
      __syncthreads();
      // head: reads hls only; next write to hls is after the NEXT barrier -> no 3rd barrier needed
      if (j < 320) {
        float4 hv = ((const float4*)hls)[hseg];
        float acc = wo.x*hv.x + wo.y*hv.y + wo.z*hv.z + wo.w*hv.w;
        acc += __shfl_xor(acc, 1, 32);
        acc += __shfl_xor(acc, 2, 32);
        acc += __shfl_xor(acc, 4, 32);
        acc += __shfl_xor(acc, 8, 32);
        acc += __shfl_xor(acc, 16, 32);
        if (hseg == 0) outb[(size_t)(t+cc)*NB + hn] = acc + bo;
      }
    }
    t += C;
  }

  // -------- Phase B: t >= T0 (constant input), with convergence detect --------
  if (T0 < T_STEPS) {
    if (j < HDIM) s0ls[j] = hsb[(size_t)(T0-1)*HDIM + j];
    __syncthreads();
    float xps = bias;
    const float4* s04 = (const float4*)s0ls;
    #pragma unroll
    for (int k4 = 0; k4 < 32; k4++) {
      float4 sv = s04[k4];
      xps += wih1T[(4*k4+0)*G4 + j]*sv.x + wih1T[(4*k4+1)*G4 + j]*sv.y
           + wih1T[(4*k4+2)*G4 + j]*sv.z + wih1T[(4*k4+3)*G4 + j]*sv.w;
    }
    for (; t < T_STEPS; ++t) {
      float a0 = xps, a1 = 0.f, a2 = 0.f, a3 = 0.f;
      const float4* h4 = (const float4*)hls;
      #pragma unroll
      for (int k = 0; k < 32; k++) {
        float4 hv = h4[k];
        a0 += w4[k].x*hv.x; a1 += w4[k].y*hv.y; a2 += w4[k].z*hv.z; a3 += w4[k].w*hv.w;
      }
      gls[j] = (a0+a1)+(a2+a3);
      __syncthreads();
      if (j < HDIM) {
        float i = sigf(gls[j]), f = sigf(gls[128+j]), g = tanh_(gls[256+j]), o = sigf(gls[384+j]);
        float nc = f*c + i*g;
        float nh = o*tanh_(nc);
        bool ok = fabsf(nh-hp) <= EPS && fabsf(nc-c) <= EPS*fmaxf(1.f, fabsf(nc));
        c = nc; hp = nh;
        hls[j] = nh;
        unsigned long long bal = __ballot(ok);
        if ((j & 63) == 0) okw[j >> 6] = (bal == ~0ull) ? 1 : 0;
      }
      __syncthreads();
      if (j < 320) {
        float4 hv = ((const float4*)hls)[hseg];
        float acc = wo.x*hv.x + wo.y*hv.y + wo.z*hv.z + wo.w*hv.w;
        acc += __shfl_xor(acc, 1, 32);
        acc += __shfl_xor(acc, 2, 32);
        acc += __shfl_xor(acc, 4, 32);
        acc += __shfl_xor(acc, 8, 32);
        acc += __shfl_xor(acc, 16, 32);
        if (hseg == 0) outb[(size_t)t*NB + hn] = acc + bo;
      }
      cnt = (okw[0] && okw[1]) ? cnt + 1 : 0;
      if (cnt >= WIN) { ++t; break; }
    }
  }
  if (j == 0) T1out[b] = t;
  // out* from the final h (frozen value when T1 < T_STEPS)
  if (j < 320) {
    float4 hv = ((const float4*)hls)[hseg];
    float acc = wo.x*hv.x + wo.y*hv.y + wo.z*hv.z + wo.w*hv.w;
    acc += __shfl_xor(acc, 1, 32);
    acc += __shfl_xor(acc, 2, 32);
    acc += __shfl_xor(acc, 4, 32);
    acc += __shfl_xor(acc, 8, 32);
    acc += __shfl_xor(acc, 16, 32);
    if (hseg == 0) outstar[b*NB + hn] = acc + bo;
  }
}

// ---------------- K4: fill t >= T1 with out* ----------------
__global__ void k4_fill(const int* __restrict__ T1in, const float* __restrict__ outstar, float* __restrict__ out)
{
  int idx = blockIdx.x*256 + threadIdx.x;
  if (idx >= 2*T_STEPS*NB) return;
  int n = idx % NB;
  int bt = idx / NB;
  int t = bt % T_STEPS;
  int b = bt / T_STEPS;
  if (t >= T1in[b]) out[idx] = outstar[b*NB + n];
}

extern "C" void kernel_launch(void* const* d_in, const int* in_sizes, int n_in,
                              void* d_out, int out_size, void* d_ws, size_t ws_size,
                              hipStream_t stream) {
  const float* x     = (const float*)d_in[0];
  const float* w1    = (const float*)d_in[1];
  const float* b1    = (const float*)d_in[2];
  const float* w2    = (const float*)d_in[3];
  const float* b2    = (const float*)d_in[4];
  const float* w_ih0 = (const float*)d_in[5];
  const float* w_hh0 = (const float*)d_in[6];
  const float* b_ih0 = (const float*)d_in[7];
  const float* b_hh0 = (const float*)d_in[8];
  const float* w_ih1 = (const float*)d_in[9];
  const float* w_hh1 = (const float*)d_in[10];
  const float* b_ih1 = (const float*)d_in[11];
  const float* b_hh1 = (const float*)d_in[12];
  const float* w_out = (const float*)d_in[13];
  const float* b_out = (const float*)d_in[14];
  float* out = (float*)d_out;

  char* ws = (char*)d_ws;
  float* xproj0  = (float*)(ws + 0);        // 2*512*4   = 4096 B
  float* wih1T   = (float*)(ws + 4096);     // 128*512*4 = 262144 B
  int*   T0      = (int*)  (ws + 266240);   // 8 B
  int*   T1      = (int*)  (ws + 266248);   // 8 B
  float* outstar = (float*)(ws + 266256);   // 80 B
  float* hs0     = (float*)(ws + 270336);   // 2*144000*128*4 = 147456000 B

  k1_setup<<<1, 256, 0, stream>>>(x, w1, b1, w2, b2, w_ih0, b_ih0, b_hh0, w_ih1, xproj0, wih1T);
  k2_lstm0<<<2, 512, 0, stream>>>(xproj0, w_hh0, hs0, T0);
  k3_lstm1<<<2, 512, 0, stream>>>(wih1T, w_hh1, b_ih1, b_hh1, hs0, T0, w_out, b_out, out, T1, outstar);
  k4_fill<<<11250, 256, 0, stream>>>(T1, outstar, out);
}

// Round 3
// 257.545 us; speedup vs baseline: 1.6404x; 1.1194x over previous
//
#include <hip/hip_runtime.h>

#define T_STEPS 144000
#define HDIM 128
#define G4 512
#define NB 10
#define CH 16
#define EPS 1e-5f
#define WIN 16
#define SENT 0x7fffffff

__device__ __forceinline__ float sigf(float x){ return 1.f/(1.f+__expf(-x)); }
__device__ __forceinline__ float tanh_(float x){
  float e2 = __expf(-2.f*fabsf(x));
  float r = (1.f - e2)/(1.f + e2);
  return copysignf(r, x);
}

// ---------------- K1: encoder MLP + xproj0 + w_ih1 transpose + flag init ----------------
__global__ void k1_setup(const float* __restrict__ x, const float* __restrict__ w1, const float* __restrict__ b1,
                         const float* __restrict__ w2, const float* __restrict__ b2,
                         const float* __restrict__ w_ih0, const float* __restrict__ b_ih0, const float* __restrict__ b_hh0,
                         const float* __restrict__ w_ih1,
                         float* __restrict__ xproj0, float* __restrict__ wih1T,
                         int* __restrict__ prog0, int* __restrict__ T0arr)
{
  __shared__ float lat1[2][64];
  __shared__ float lat2[2][128];
  const int tid = threadIdx.x;
  if (tid < 2) { prog0[tid] = 0; T0arr[tid] = SENT; }
  if (tid < 128) {
    int b = tid >> 6, jj = tid & 63;
    float a = b1[jj];
    #pragma unroll
    for (int k = 0; k < 16; k++) a += x[b*16+k] * w1[jj*16+k];
    lat1[b][jj] = fmaxf(a, 0.f);
  }
  __syncthreads();
  {
    int b = tid >> 7, jj = tid & 127;
    float a = b2[jj];
    #pragma unroll
    for (int k = 0; k < 64; k++) a += lat1[b][k] * w2[jj*64+k];
    lat2[b][jj] = fmaxf(a, 0.f);
  }
  __syncthreads();
  for (int idx = tid; idx < 2*G4; idx += 256) {
    int b = idx >> 9, jj = idx & 511;
    float a = b_ih0[jj] + b_hh0[jj];
    #pragma unroll
    for (int k = 0; k < 128; k++) a += lat2[b][k] * w_ih0[jj*128+k];
    xproj0[idx] = a;
  }
  // transpose w_ih1 [512][128] -> wih1T [128][512]
  for (int idx = tid; idx < G4*HDIM; idx += 256) {
    int k = idx >> 9, jj = idx & 511;
    wih1T[idx] = w_ih1[jj*128 + k];
  }
}

// ---------------- Fused K2+K3: pipelined two-layer recurrence ----------------
// blocks 0,1: layer-0 producer (batch 0,1). blocks 2,3: layer-1 consumer (batch 0,1).
__global__ __launch_bounds__(512) void k23_fused(
    const float* __restrict__ xproj0, const float* __restrict__ w_hh0,
    const float* __restrict__ wih1T, const float* __restrict__ w_hh1,
    const float* __restrict__ b_ih1, const float* __restrict__ b_hh1,
    const float* __restrict__ w_out, const float* __restrict__ b_out,
    float* __restrict__ hs0, int* __restrict__ prog0, int* __restrict__ T0arr,
    float* __restrict__ out, int* __restrict__ T1out, float* __restrict__ outstar)
{
  const int role = blockIdx.x >> 1;
  const int b = blockIdx.x & 1;
  const int j = threadIdx.x;

  if (role == 0) {
    // ================= layer-0 producer =================
    __shared__ __align__(16) float hls[HDIM];
    __shared__ float gls[G4];
    __shared__ int okw[2];
    float4 w4[32];
    const float4* wr = (const float4*)(w_hh0 + j*128);
    #pragma unroll
    for (int k = 0; k < 32; k++) w4[k] = wr[k];
    const float xp = xproj0[b*G4 + j];
    float* hb = hs0 + (size_t)b * T_STEPS * HDIM;
    if (j < HDIM) hls[j] = 0.f;
    float c = 0.f, hp = 0.f;
    int cnt = 0;
    __syncthreads();
    int t = 0;
    for (; t < T_STEPS; ++t) {
      float a0 = xp, a1 = 0.f, a2 = 0.f, a3 = 0.f;
      const float4* h4 = (const float4*)hls;
      #pragma unroll
      for (int k = 0; k < 32; k++) {
        float4 hv = h4[k];
        a0 += w4[k].x*hv.x; a1 += w4[k].y*hv.y; a2 += w4[k].z*hv.z; a3 += w4[k].w*hv.w;
      }
      gls[j] = (a0+a1)+(a2+a3);
      __syncthreads();
      if (j < HDIM) {
        float i = sigf(gls[j]), f = sigf(gls[128+j]), g = tanh_(gls[256+j]), o = sigf(gls[384+j]);
        float nc = f*c + i*g;
        float nh = o*tanh_(nc);
        bool ok = fabsf(nh-hp) <= EPS && fabsf(nc-c) <= EPS*fmaxf(1.f, fabsf(nc));
        c = nc; hp = nh;
        hls[j] = nh;
        hb[(size_t)t*HDIM + j] = nh;
        unsigned long long bal = __ballot(ok);
        if ((j & 63) == 0) okw[j >> 6] = (bal == ~0ull) ? 1 : 0;
      }
      __syncthreads();
      if (j == 0 && (t & (CH-1)) == (CH-1)) {
        __threadfence();
        __hip_atomic_store(&prog0[b], t+1, __ATOMIC_RELEASE, __HIP_MEMORY_SCOPE_AGENT);
      }
      cnt = (okw[0] && okw[1]) ? cnt + 1 : 0;
      if (cnt >= WIN) { ++t; break; }
    }
    if (j == 0) {
      __threadfence();
      __hip_atomic_store(&prog0[b], t, __ATOMIC_RELEASE, __HIP_MEMORY_SCOPE_AGENT);
      __hip_atomic_store(&T0arr[b], t, __ATOMIC_RELEASE, __HIP_MEMORY_SCOPE_AGENT);
    }
  } else {
    // ================= layer-1 consumer + fused head =================
    __shared__ __align__(16) float hls[HDIM];
    __shared__ float gls[G4];
    __shared__ __align__(16) float s0ls[CH*HDIM];
    __shared__ int okw[2];
    __shared__ int sAv, sT0;
    float4 w4[32];
    const float4* wr = (const float4*)(w_hh1 + j*128);
    #pragma unroll
    for (int k = 0; k < 32; k++) w4[k] = wr[k];
    const float bias = b_ih1[j] + b_hh1[j];
    const int hn = j >> 5, hseg = j & 31;
    float4 wo = make_float4(0.f,0.f,0.f,0.f); float bo = 0.f;
    if (j < 320) { wo = ((const float4*)(w_out + hn*128))[hseg]; bo = b_out[hn]; }
    float* outb = out + (size_t)b * T_STEPS * NB;
    const float* hsb = hs0 + (size_t)b * T_STEPS * HDIM;
    if (j < HDIM) hls[j] = 0.f;
    float c = 0.f, hp = 0.f;
    int cnt = 0;
    __syncthreads();
    int t = 0, T0fin = T_STEPS;

    // -------- Phase A: t < T0 (time-varying input streamed from producer) --------
    for (;;) {
      if (j == 0) {
        int av, T0v;
        for (;;) {
          av  = __hip_atomic_load(&prog0[b], __ATOMIC_ACQUIRE, __HIP_MEMORY_SCOPE_AGENT);
          T0v = __hip_atomic_load(&T0arr[b], __ATOMIC_ACQUIRE, __HIP_MEMORY_SCOPE_AGENT);
          int need = t + CH;
          if (T0v != SENT && T0v < need) need = T0v;
          if ((T0v != SENT && t >= T0v) || av >= need) break;
          __builtin_amdgcn_s_sleep(4);
        }
        sAv = av; sT0 = T0v;
      }
      __syncthreads();
      __threadfence();  // make producer's published hs0 visible to all lanes
      int T0v = sT0, av = sAv;
      if (T0v != SENT && t >= T0v) { T0fin = T0v; break; }
      int lim = (T0v != SENT && T0v < av) ? T0v : av;
      int C = min(CH, lim - t);
      for (int idx = j; idx < CH*HDIM; idx += 512) {
        float v = 0.f;
        if (idx < C*HDIM) v = hsb[(size_t)t*HDIM + idx];
        s0ls[idx] = v;
      }
      __syncthreads();
      float xpa[CH];
      #pragma unroll
      for (int cc = 0; cc < CH; cc++) xpa[cc] = 0.f;
      const float4* s04 = (const float4*)s0ls;
      for (int k4 = 0; k4 < 32; k4++) {
        float wv0 = wih1T[(4*k4+0)*G4 + j];
        float wv1 = wih1T[(4*k4+1)*G4 + j];
        float wv2 = wih1T[(4*k4+2)*G4 + j];
        float wv3 = wih1T[(4*k4+3)*G4 + j];
        #pragma unroll
        for (int cc = 0; cc < CH; cc++) {
          float4 sv = s04[cc*32 + k4];
          xpa[cc] += wv0*sv.x + wv1*sv.y + wv2*sv.z + wv3*sv.w;
        }
      }
      for (int cc = 0; cc < C; cc++) {
        float a0 = xpa[cc] + bias, a1 = 0.f, a2 = 0.f, a3 = 0.f;
        const float4* h4 = (const float4*)hls;
        #pragma unroll
        for (int k = 0; k < 32; k++) {
          float4 hv = h4[k];
          a0 += w4[k].x*hv.x; a1 += w4[k].y*hv.y; a2 += w4[k].z*hv.z; a3 += w4[k].w*hv.w;
        }
        gls[j] = (a0+a1)+(a2+a3);
        __syncthreads();
        if (j < HDIM) {
          float i = sigf(gls[j]), f = sigf(gls[128+j]), g = tanh_(gls[256+j]), o = sigf(gls[384+j]);
          float nc = f*c + i*g;
          float nh = o*tanh_(nc);
          c = nc; hp = nh;
          hls[j] = nh;
        }
        __syncthreads();
        if (j < 320) {
          float4 hv = ((const float4*)hls)[hseg];
          float acc = wo.x*hv.x + wo.y*hv.y + wo.z*hv.z + wo.w*hv.w;
          acc += __shfl_xor(acc, 1, 32);
          acc += __shfl_xor(acc, 2, 32);
          acc += __shfl_xor(acc, 4, 32);
          acc += __shfl_xor(acc, 8, 32);
          acc += __shfl_xor(acc, 16, 32);
          if (hseg == 0) outb[(size_t)(t+cc)*NB + hn] = acc + bo;
        }
      }
      t += C;
    }

    // -------- Phase B: t >= T0 (constant input), convergence detect --------
    if (T0fin < T_STEPS) {
      if (j < HDIM) s0ls[j] = hsb[(size_t)(T0fin-1)*HDIM + j];
      __syncthreads();
      float xps = bias;
      const float4* s04 = (const float4*)s0ls;
      #pragma unroll
      for (int k4 = 0; k4 < 32; k4++) {
        float4 sv = s04[k4];
        xps += wih1T[(4*k4+0)*G4 + j]*sv.x + wih1T[(4*k4+1)*G4 + j]*sv.y
             + wih1T[(4*k4+2)*G4 + j]*sv.z + wih1T[(4*k4+3)*G4 + j]*sv.w;
      }
      for (; t < T_STEPS; ++t) {
        float a0 = xps, a1 = 0.f, a2 = 0.f, a3 = 0.f;
        const float4* h4 = (const float4*)hls;
        #pragma unroll
        for (int k = 0; k < 32; k++) {
          float4 hv = h4[k];
          a0 += w4[k].x*hv.x; a1 += w4[k].y*hv.y; a2 += w4[k].z*hv.z; a3 += w4[k].w*hv.w;
        }
        gls[j] = (a0+a1)+(a2+a3);
        __syncthreads();
        if (j < HDIM) {
          float i = sigf(gls[j]), f = sigf(gls[128+j]), g = tanh_(gls[256+j]), o = sigf(gls[384+j]);
          float nc = f*c + i*g;
          float nh = o*tanh_(nc);
          bool ok = fabsf(nh-hp) <= EPS && fabsf(nc-c) <= EPS*fmaxf(1.f, fabsf(nc));
          c = nc; hp = nh;
          hls[j] = nh;
          unsigned long long bal = __ballot(ok);
          if ((j & 63) == 0) okw[j >> 6] = (bal == ~0ull) ? 1 : 0;
        }
        __syncthreads();
        if (j < 320) {
          float4 hv = ((const float4*)hls)[hseg];
          float acc = wo.x*hv.x + wo.y*hv.y + wo.z*hv.z + wo.w*hv.w;
          acc += __shfl_xor(acc, 1, 32);
          acc += __shfl_xor(acc, 2, 32);
          acc += __shfl_xor(acc, 4, 32);
          acc += __shfl_xor(acc, 8, 32);
          acc += __shfl_xor(acc, 16, 32);
          if (hseg == 0) outb[(size_t)t*NB + hn] = acc + bo;
        }
        cnt = (okw[0] && okw[1]) ? cnt + 1 : 0;
        if (cnt >= WIN) { ++t; break; }
      }
    }
    if (j == 0) T1out[b] = t;
    if (j < 320) {
      float4 hv = ((const float4*)hls)[hseg];
      float acc = wo.x*hv.x + wo.y*hv.y + wo.z*hv.z + wo.w*hv.w;
      acc += __shfl_xor(acc, 1, 32);
      acc += __shfl_xor(acc, 2, 32);
      acc += __shfl_xor(acc, 4, 32);
      acc += __shfl_xor(acc, 8, 32);
      acc += __shfl_xor(acc, 16, 32);
      if (hseg == 0) outstar[b*NB + hn] = acc + bo;
    }
  }
}

// ---------------- K4: fill t >= T1 with out* ----------------
__global__ void k4_fill(const int* __restrict__ T1in, const float* __restrict__ outstar, float* __restrict__ out)
{
  int idx = blockIdx.x*256 + threadIdx.x;
  if (idx >= 2*T_STEPS*NB) return;
  int n = idx % NB;
  int bt = idx / NB;
  int t = bt % T_STEPS;
  int b = bt / T_STEPS;
  if (t >= T1in[b]) out[idx] = outstar[b*NB + n];
}

extern "C" void kernel_launch(void* const* d_in, const int* in_sizes, int n_in,
                              void* d_out, int out_size, void* d_ws, size_t ws_size,
                              hipStream_t stream) {
  const float* x     = (const float*)d_in[0];
  const float* w1    = (const float*)d_in[1];
  const float* b1    = (const float*)d_in[2];
  const float* w2    = (const float*)d_in[3];
  const float* b2    = (const float*)d_in[4];
  const float* w_ih0 = (const float*)d_in[5];
  const float* w_hh0 = (const float*)d_in[6];
  const float* b_ih0 = (const float*)d_in[7];
  const float* b_hh0 = (const float*)d_in[8];
  const float* w_ih1 = (const float*)d_in[9];
  const float* w_hh1 = (const float*)d_in[10];
  const float* b_ih1 = (const float*)d_in[11];
  const float* b_hh1 = (const float*)d_in[12];
  const float* w_out = (const float*)d_in[13];
  const float* b_out = (const float*)d_in[14];
  float* out = (float*)d_out;

  char* ws = (char*)d_ws;
  float* xproj0  = (float*)(ws + 0);        // 4096 B
  float* wih1T   = (float*)(ws + 4096);     // 262144 B
  int*   T0arr   = (int*)  (ws + 266240);   // 8 B
  int*   T1      = (int*)  (ws + 266248);   // 8 B
  float* outstar = (float*)(ws + 266256);   // 80 B
  int*   prog0   = (int*)  (ws + 266336);   // 8 B
  float* hs0     = (float*)(ws + 270336);   // 2*144000*128*4 B

  k1_setup<<<1, 256, 0, stream>>>(x, w1, b1, w2, b2, w_ih0, b_ih0, b_hh0, w_ih1,
                                  xproj0, wih1T, prog0, T0arr);
  k23_fused<<<4, 512, 0, stream>>>(xproj0, w_hh0, wih1T, w_hh1, b_ih1, b_hh1,
                                   w_out, b_out, hs0, prog0, T0arr, out, T1, outstar);
  k4_fill<<<11250, 256, 0, stream>>>(T1, outstar, out);
}

// Round 4
// 132.658 us; speedup vs baseline: 3.1847x; 1.9414x over previous
//
#include <hip/hip_runtime.h>

#define T_STEPS 144000
#define HDIM 128
#define G4 512
#define NB 10
#define CH 16
#define EPS 1e-4f
#define WIN 8
#define SENT 0x7fffffff
#define RING0 4096         // hs0 ring (steps)
#define R0M (RING0-1)
#define RING1 1024         // xproj1 ring (steps)
#define R1M (RING1-1)

__device__ __forceinline__ float sigf(float x){ return 1.f/(1.f+__expf(-x)); }
__device__ __forceinline__ float tanh_(float x){
  float e2 = __expf(-2.f*fabsf(x));
  float r = (1.f - e2)/(1.f + e2);
  return copysignf(r, x);
}

// ---------------- K1: encoder MLP + xproj0 + w_ih1 transpose (LDS-tiled) + flag init ----------------
__global__ void k1_setup(const float* __restrict__ x, const float* __restrict__ w1, const float* __restrict__ b1,
                         const float* __restrict__ w2, const float* __restrict__ b2,
                         const float* __restrict__ w_ih0, const float* __restrict__ b_ih0, const float* __restrict__ b_hh0,
                         const float* __restrict__ w_ih1,
                         float* __restrict__ xproj0, float* __restrict__ wih1T,
                         int* __restrict__ prog0, int* __restrict__ T0arr,
                         int* __restrict__ progP, int* __restrict__ progC)
{
  __shared__ float lat1[2][64];
  __shared__ float lat2[2][128];
  __shared__ float tile[32][33];
  const int tid = threadIdx.x;
  if (tid < 2) { prog0[tid] = 0; T0arr[tid] = SENT; progP[tid] = 0; progC[tid] = 0; }
  if (tid < 128) {
    int b = tid >> 6, jj = tid & 63;
    float a = b1[jj];
    #pragma unroll
    for (int k = 0; k < 16; k++) a += x[b*16+k] * w1[jj*16+k];
    lat1[b][jj] = fmaxf(a, 0.f);
  }
  __syncthreads();
  {
    int b = tid >> 7, jj = tid & 127;
    float a = b2[jj];
    #pragma unroll
    for (int k = 0; k < 64; k++) a += lat1[b][k] * w2[jj*64+k];
    lat2[b][jj] = fmaxf(a, 0.f);
  }
  __syncthreads();
  for (int idx = tid; idx < 2*G4; idx += 256) {
    int b = idx >> 9, jj = idx & 511;
    float a = b_ih0[jj] + b_hh0[jj];
    #pragma unroll
    for (int k = 0; k < 128; k++) a += lat2[b][k] * w_ih0[jj*128+k];
    xproj0[idx] = a;
  }
  // LDS-tiled transpose: w_ih1 [512][128] -> wih1T [128][512]
  const int tx = tid & 31, ty = tid >> 5;  // ty in 0..7
  for (int ti = 0; ti < 16; ti++) {
    for (int tk = 0; tk < 4; tk++) {
      #pragma unroll
      for (int p = 0; p < 4; p++)
        tile[ty + 8*p][tx] = w_ih1[(ti*32 + ty + 8*p)*128 + tk*32 + tx];
      __syncthreads();
      #pragma unroll
      for (int p = 0; p < 4; p++)
        wih1T[(tk*32 + ty + 8*p)*512 + ti*32 + tx] = tile[tx][ty + 8*p];
      __syncthreads();
    }
  }
}

// ---------------- Fused: 3-stage pipeline ----------------
// blocks 0,1: layer-0 producer.  blocks 2,3: input-projection ("projector").
// blocks 4,5: layer-1 consumer + fused head.
__global__ __launch_bounds__(512) void k23_fused(
    const float* __restrict__ xproj0, const float* __restrict__ w_hh0,
    const float* __restrict__ wih1T, const float* __restrict__ w_hh1,
    const float* __restrict__ b_ih1, const float* __restrict__ b_hh1,
    const float* __restrict__ w_out, const float* __restrict__ b_out,
    float* __restrict__ hs0, float* __restrict__ xproj1,
    int* __restrict__ prog0, int* __restrict__ T0arr,
    int* __restrict__ progP, int* __restrict__ progC,
    float* __restrict__ out, int* __restrict__ T1out, float* __restrict__ outstar)
{
  const int role = blockIdx.x >> 1;
  const int b = blockIdx.x & 1;
  const int j = threadIdx.x;
  const int gt = j >> 7;   // 0:i 1:f 2:g 3:o (wave-uniform)

  if (role == 0) {
    // ================= layer-0 producer =================
    __shared__ __align__(16) float hls[HDIM];
    __shared__ float gls[G4];
    __shared__ int okw[2];
    float4 w4[32];
    const float4* wr = (const float4*)(w_hh0 + j*128);
    #pragma unroll
    for (int k = 0; k < 32; k++) w4[k] = wr[k];
    const float xp = xproj0[b*G4 + j];
    float* hb = hs0 + (size_t)b * RING0 * HDIM;
    if (j < HDIM) hls[j] = 0.f;
    float c = 0.f, hp = 0.f;
    int cnt = 0;
    __syncthreads();
    int t = 0;
    for (; t < T_STEPS; ++t) {
      float a0 = xp, a1 = 0.f, a2 = 0.f, a3 = 0.f;
      const float4* h4 = (const float4*)hls;
      #pragma unroll
      for (int k = 0; k < 32; k++) {
        float4 hv = h4[k];
        a0 += w4[k].x*hv.x; a1 += w4[k].y*hv.y; a2 += w4[k].z*hv.z; a3 += w4[k].w*hv.w;
      }
      float pre = (a0+a1)+(a2+a3);
      float act;
      if (gt == 2) act = tanh_(pre); else act = sigf(pre);
      gls[j] = act;
      __syncthreads();
      if (j < HDIM) {
        float ii = gls[j], ff = gls[128+j], gg = gls[256+j], oo = gls[384+j];
        float nc = ff*c + ii*gg;
        float nh = oo*tanh_(nc);
        bool ok = fabsf(nh-hp) <= EPS && fabsf(nc-c) <= EPS*fmaxf(1.f, fabsf(nc));
        c = nc; hp = nh;
        hls[j] = nh;
        hb[(size_t)(t & R0M)*HDIM + j] = nh;
        unsigned long long bal = __ballot(ok);
        if ((j & 63) == 0) okw[j >> 6] = (bal == ~0ull) ? 1 : 0;
      }
      __syncthreads();
      if (j == 0 && (t & (CH-1)) == (CH-1)) {
        __threadfence();
        __hip_atomic_store(&prog0[b], t+1, __ATOMIC_RELEASE, __HIP_MEMORY_SCOPE_AGENT);
        // ring0 backpressure for next chunk (others stall at next bar1)
        while ((t + 1 + CH) - __hip_atomic_load(&progP[b], __ATOMIC_ACQUIRE, __HIP_MEMORY_SCOPE_AGENT) > RING0)
          __builtin_amdgcn_s_sleep(2);
      }
      cnt = (okw[0] && okw[1]) ? cnt + 1 : 0;
      if (cnt >= WIN) { ++t; break; }
    }
    if (j == 0) {
      __threadfence();
      __hip_atomic_store(&prog0[b], t, __ATOMIC_RELEASE, __HIP_MEMORY_SCOPE_AGENT);
      __hip_atomic_store(&T0arr[b], t, __ATOMIC_RELEASE, __HIP_MEMORY_SCOPE_AGENT);
    }
  } else if (role == 1) {
    // ================= projector: xproj1 = w_ih1 . h0 + bias (ring) =================
    __shared__ __align__(16) float s0ls[CH*HDIM];
    __shared__ int sAv, sT0;
    const float bias = b_ih1[j] + b_hh1[j];
    const float* hb = hs0 + (size_t)b * RING0 * HDIM;
    float* xp1b = xproj1 + (size_t)b * RING1 * G4;
    int t = 0;
    for (;;) {
      if (j == 0) {
        int av, T0v;
        for (;;) {
          av  = __hip_atomic_load(&prog0[b], __ATOMIC_ACQUIRE, __HIP_MEMORY_SCOPE_AGENT);
          T0v = __hip_atomic_load(&T0arr[b], __ATOMIC_ACQUIRE, __HIP_MEMORY_SCOPE_AGENT);
          if (T0v != SENT && t >= T0v) break;
          int need = t + CH; if (T0v != SENT && T0v < need) need = T0v;
          int cons = __hip_atomic_load(&progC[b], __ATOMIC_ACQUIRE, __HIP_MEMORY_SCOPE_AGENT);
          if (av >= need && need <= cons + RING1) break;
          __builtin_amdgcn_s_sleep(2);
        }
        sAv = av; sT0 = T0v;
      }
      __syncthreads();
      __threadfence();
      int T0v = sT0, av = sAv;
      if (T0v != SENT && t >= T0v) break;
      int lim = (T0v != SENT && T0v < av) ? T0v : av;
      int C = min(CH, lim - t);
      for (int idx = j; idx < CH*HDIM; idx += 512) {
        int cc = idx >> 7, lane = idx & 127;
        float v = 0.f;
        if (cc < C) v = hb[(size_t)((t + cc) & R0M)*HDIM + lane];
        s0ls[idx] = v;
      }
      __syncthreads();
      float xpa[CH];
      #pragma unroll
      for (int cc = 0; cc < CH; cc++) xpa[cc] = 0.f;
      const float4* s04 = (const float4*)s0ls;
      for (int k4 = 0; k4 < 32; k4++) {
        float wv0 = wih1T[(4*k4+0)*G4 + j];
        float wv1 = wih1T[(4*k4+1)*G4 + j];
        float wv2 = wih1T[(4*k4+2)*G4 + j];
        float wv3 = wih1T[(4*k4+3)*G4 + j];
        #pragma unroll
        for (int cc = 0; cc < CH; cc++) {
          float4 sv = s04[cc*32 + k4];
          xpa[cc] += wv0*sv.x + wv1*sv.y + wv2*sv.z + wv3*sv.w;
        }
      }
      for (int cc = 0; cc < C; cc++)
        xp1b[(size_t)((t + cc) & R1M)*G4 + j] = xpa[cc] + bias;
      __syncthreads();
      if (j == 0) {
        __threadfence();
        __hip_atomic_store(&progP[b], t + C, __ATOMIC_RELEASE, __HIP_MEMORY_SCOPE_AGENT);
      }
      t += C;
    }
  } else {
    // ================= layer-1 consumer + fused head =================
    __shared__ __align__(16) float hls[HDIM];
    __shared__ float gls[G4];
    __shared__ __align__(16) float s0b[HDIM];
    __shared__ int okw[2];
    __shared__ int sAv, sT0;
    float4 w4[32];
    const float4* wr = (const float4*)(w_hh1 + j*128);
    #pragma unroll
    for (int k = 0; k < 32; k++) w4[k] = wr[k];
    const float bias = b_ih1[j] + b_hh1[j];
    const int hn = j >> 5, hseg = j & 31;
    float4 wo = make_float4(0.f,0.f,0.f,0.f); float bo = 0.f;
    if (j < 320) { wo = ((const float4*)(w_out + hn*128))[hseg]; bo = b_out[hn]; }
    float* outb = out + (size_t)b * T_STEPS * NB;
    const float* hb = hs0 + (size_t)b * RING0 * HDIM;
    const float* xp1b = xproj1 + (size_t)b * RING1 * G4;
    if (j < HDIM) hls[j] = 0.f;
    float c = 0.f, hp = 0.f;
    int cnt = 0;
    __syncthreads();
    int t = 0, T0fin = T_STEPS;

    // -------- Phase A: t < T0, input = xproj1 ring --------
    for (;;) {
      if (j == 0) {
        int pv, T0v;
        for (;;) {
          pv  = __hip_atomic_load(&progP[b], __ATOMIC_ACQUIRE, __HIP_MEMORY_SCOPE_AGENT);
          T0v = __hip_atomic_load(&T0arr[b], __ATOMIC_ACQUIRE, __HIP_MEMORY_SCOPE_AGENT);
          if (T0v != SENT && t >= T0v) break;
          int need = t + CH; if (T0v != SENT && T0v < need) need = T0v;
          if (pv >= need) break;
          __builtin_amdgcn_s_sleep(2);
        }
        sAv = pv; sT0 = T0v;
      }
      __syncthreads();
      __threadfence();
      int T0v = sT0, pv = sAv;
      if (T0v != SENT && t >= T0v) { T0fin = T0v; break; }
      int lim = (T0v != SENT && T0v < pv) ? T0v : pv;
      int C = min(CH, lim - t);
      float xpa[CH];
      #pragma unroll
      for (int cc = 0; cc < CH; cc++)
        xpa[cc] = xp1b[(size_t)((t + cc) & R1M)*G4 + j];
      for (int cc = 0; cc < C; cc++) {
        float a0 = xpa[cc], a1 = 0.f, a2 = 0.f, a3 = 0.f;
        const float4* h4 = (const float4*)hls;
        #pragma unroll
        for (int k = 0; k < 32; k++) {
          float4 hv = h4[k];
          a0 += w4[k].x*hv.x; a1 += w4[k].y*hv.y; a2 += w4[k].z*hv.z; a3 += w4[k].w*hv.w;
        }
        float pre = (a0+a1)+(a2+a3);
        float act;
        if (gt == 2) act = tanh_(pre); else act = sigf(pre);
        gls[j] = act;
        __syncthreads();
        if (j < HDIM) {
          float ii = gls[j], ff = gls[128+j], gg = gls[256+j], oo = gls[384+j];
          float nc = ff*c + ii*gg;
          float nh = oo*tanh_(nc);
          c = nc; hp = nh;
          hls[j] = nh;
        }
        __syncthreads();
        if (j < 320) {
          float4 hv = ((const float4*)hls)[hseg];
          float acc = wo.x*hv.x + wo.y*hv.y + wo.z*hv.z + wo.w*hv.w;
          acc += __shfl_xor(acc, 1, 32);
          acc += __shfl_xor(acc, 2, 32);
          acc += __shfl_xor(acc, 4, 32);
          acc += __shfl_xor(acc, 8, 32);
          acc += __shfl_xor(acc, 16, 32);
          if (hseg == 0) outb[(size_t)(t+cc)*NB + hn] = acc + bo;
        }
      }
      if (j == 0) __hip_atomic_store(&progC[b], t + C, __ATOMIC_RELEASE, __HIP_MEMORY_SCOPE_AGENT);
      t += C;
    }

    // -------- Phase B: t >= T0 (constant input), convergence detect --------
    if (T0fin < T_STEPS) {
      if (j < HDIM) s0b[j] = hb[(size_t)((T0fin-1) & R0M)*HDIM + j];
      __syncthreads();
      float xps = bias;
      const float4* s04 = (const float4*)s0b;
      #pragma unroll
      for (int k4 = 0; k4 < 32; k4++) {
        float4 sv = s04[k4];
        xps += wih1T[(4*k4+0)*G4 + j]*sv.x + wih1T[(4*k4+1)*G4 + j]*sv.y
             + wih1T[(4*k4+2)*G4 + j]*sv.z + wih1T[(4*k4+3)*G4 + j]*sv.w;
      }
      for (; t < T_STEPS; ++t) {
        float a0 = xps, a1 = 0.f, a2 = 0.f, a3 = 0.f;
        const float4* h4 = (const float4*)hls;
        #pragma unroll
        for (int k = 0; k < 32; k++) {
          float4 hv = h4[k];
          a0 += w4[k].x*hv.x; a1 += w4[k].y*hv.y; a2 += w4[k].z*hv.z; a3 += w4[k].w*hv.w;
        }
        float pre = (a0+a1)+(a2+a3);
        float act;
        if (gt == 2) act = tanh_(pre); else act = sigf(pre);
        gls[j] = act;
        __syncthreads();
        if (j < HDIM) {
          float ii = gls[j], ff = gls[128+j], gg = gls[256+j], oo = gls[384+j];
          float nc = ff*c + ii*gg;
          float nh = oo*tanh_(nc);
          bool ok = fabsf(nh-hp) <= EPS && fabsf(nc-c) <= EPS*fmaxf(1.f, fabsf(nc));
          c = nc; hp = nh;
          hls[j] = nh;
          unsigned long long bal = __ballot(ok);
          if ((j & 63) == 0) okw[j >> 6] = (bal == ~0ull) ? 1 : 0;
        }
        __syncthreads();
        if (j < 320) {
          float4 hv = ((const float4*)hls)[hseg];
          float acc = wo.x*hv.x + wo.y*hv.y + wo.z*hv.z + wo.w*hv.w;
          acc += __shfl_xor(acc, 1, 32);
          acc += __shfl_xor(acc, 2, 32);
          acc += __shfl_xor(acc, 4, 32);
          acc += __shfl_xor(acc, 8, 32);
          acc += __shfl_xor(acc, 16, 32);
          if (hseg == 0) outb[(size_t)t*NB + hn] = acc + bo;
        }
        cnt = (okw[0] && okw[1]) ? cnt + 1 : 0;
        if (cnt >= WIN) { ++t; break; }
      }
    }
    if (j == 0) T1out[b] = t;
    if (j < 320) {
      float4 hv = ((const float4*)hls)[hseg];
      float acc = wo.x*hv.x + wo.y*hv.y + wo.z*hv.z + wo.w*hv.w;
      acc += __shfl_xor(acc, 1, 32);
      acc += __shfl_xor(acc, 2, 32);
      acc += __shfl_xor(acc, 4, 32);
      acc += __shfl_xor(acc, 8, 32);
      acc += __shfl_xor(acc, 16, 32);
      if (hseg == 0) outstar[b*NB + hn] = acc + bo;
    }
  }
}

// ---------------- K4: fill t >= T1 with out* ----------------
__global__ void k4_fill(const int* __restrict__ T1in, const float* __restrict__ outstar, float* __restrict__ out)
{
  int idx = blockIdx.x*256 + threadIdx.x;
  if (idx >= 2*T_STEPS*NB) return;
  int n = idx % NB;
  int bt = idx / NB;
  int t = bt % T_STEPS;
  int b = bt / T_STEPS;
  if (t >= T1in[b]) out[idx] = outstar[b*NB + n];
}

extern "C" void kernel_launch(void* const* d_in, const int* in_sizes, int n_in,
                              void* d_out, int out_size, void* d_ws, size_t ws_size,
                              hipStream_t stream) {
  const float* x     = (const float*)d_in[0];
  const float* w1    = (const float*)d_in[1];
  const float* b1    = (const float*)d_in[2];
  const float* w2    = (const float*)d_in[3];
  const float* b2    = (const float*)d_in[4];
  const float* w_ih0 = (const float*)d_in[5];
  const float* w_hh0 = (const float*)d_in[6];
  const float* b_ih0 = (const float*)d_in[7];
  const float* b_hh0 = (const float*)d_in[8];
  const float* w_ih1 = (const float*)d_in[9];
  const float* w_hh1 = (const float*)d_in[10];
  const float* b_ih1 = (const float*)d_in[11];
  const float* b_hh1 = (const float*)d_in[12];
  const float* w_out = (const float*)d_in[13];
  const float* b_out = (const float*)d_in[14];
  float* out = (float*)d_out;

  char* ws = (char*)d_ws;
  float* xproj0  = (float*)(ws + 0);        // 4096 B
  float* wih1T   = (float*)(ws + 4096);     // 262144 B
  int*   prog0   = (int*)  (ws + 266240);   // 8 B
  int*   T0arr   = (int*)  (ws + 266248);   // 8 B
  int*   progP   = (int*)  (ws + 266256);   // 8 B
  int*   progC   = (int*)  (ws + 266264);   // 8 B
  int*   T1      = (int*)  (ws + 266272);   // 8 B
  float* outstar = (float*)(ws + 266280);   // 80 B
  float* hs0     = (float*)(ws + 270336);   // 2*4096*128*4 = 4 MB
  float* xproj1  = (float*)(ws + 270336 + 2u*RING0*HDIM*4); // 2*1024*512*4 = 4 MB

  k1_setup<<<1, 256, 0, stream>>>(x, w1, b1, w2, b2, w_ih0, b_ih0, b_hh0, w_ih1,
                                  xproj0, wih1T, prog0, T0arr, progP, progC);
  k23_fused<<<6, 512, 0, stream>>>(xproj0, w_hh0, wih1T, w_hh1, b_ih1, b_hh1,
                                   w_out, b_out, hs0, xproj1,
                                   prog0, T0arr, progP, progC, out, T1, outstar);
  k4_fill<<<11250, 256, 0, stream>>>(T1, outstar, out);
}